// Round 7
// baseline (42.652 us; speedup 1.0000x reference)
//
#include <hip/hip_runtime.h>
#include <hip/hip_bf16.h>

// Segment mean: N values, sorted segment ids, NC segments.
// Block-private accumulation: each block owns CHUNK contiguous elements.
// Sortedness => any id strictly between the block's first and last id is
// FULLY contained in the block -> accumulate in LDS, write mean directly
// to out (plain stores). Only the two edge segments per block need global
// atomics (~16K total vs ~1M before). Finalize fixes up straddlers only
// (any segment with gcnts > 0).

#define VPT 16
#define BLOCK 256
#define CHUNK (VPT * BLOCK)   // 4096 elements per block

__global__ __launch_bounds__(BLOCK)
void seg_mean_kernel(const float* __restrict__ x,
                     const void* __restrict__ seg,
                     float* __restrict__ out,
                     float* __restrict__ gsums,
                     float* __restrict__ gcnts,
                     int n) {
    __shared__ float lsum[CHUNK];
    __shared__ float lcnt[CHUNK];
    __shared__ int s_first, s_last;

    const int* s32 = (const int*)seg;
    const long long* s64 = (const long long*)seg;
    // dtype sniff: int64 storage => int32 word [n-1] is a high word (0, ids < 2^18);
    // int32 storage => largest sorted id (nonzero).
    const bool is64 = (s32[n - 1] == 0);

    const int tid = threadIdx.x;
    const long long bbase = (long long)blockIdx.x * CHUNK;
    const long long base = bbase + (long long)tid * VPT;

    int ids[VPT];
    float vals[VPT];
    int nv = 0;
    if (base < n) {
        long long rem = (long long)n - base;
        nv = (rem >= VPT) ? VPT : (int)rem;
    }

    if (nv == VPT) {
        const float4* xv = (const float4*)(x + base);
        #pragma unroll
        for (int k = 0; k < 4; ++k) {
            float4 a = xv[k];
            vals[4 * k]     = a.x;
            vals[4 * k + 1] = a.y;
            vals[4 * k + 2] = a.z;
            vals[4 * k + 3] = a.w;
        }
        if (is64) {
            // 16B load = two int64; low dwords at .x and .z (LE).
            const int4* iv = (const int4*)(s64 + base);
            #pragma unroll
            for (int k = 0; k < 8; ++k) {
                int4 t = iv[k];
                ids[2 * k]     = t.x;
                ids[2 * k + 1] = t.z;
            }
        } else {
            const int4* iv = (const int4*)(s32 + base);
            #pragma unroll
            for (int k = 0; k < 4; ++k) {
                int4 t = iv[k];
                ids[4 * k]     = t.x;
                ids[4 * k + 1] = t.y;
                ids[4 * k + 2] = t.z;
                ids[4 * k + 3] = t.w;
            }
        }
    } else {
        #pragma unroll
        for (int k = 0; k < VPT; ++k) {
            if (k < nv) {
                ids[k]  = is64 ? (int)s64[base + k] : s32[base + k];
                vals[k] = x[base + k];
            } else {
                ids[k]  = -1;
                vals[k] = 0.0f;
            }
        }
    }

    // Block first/last ids (tail-safe; grid sized so bbase < n).
    if (tid == 0) s_first = ids[0];
    {
        long long lastpos = bbase + CHUNK;
        if (lastpos > n) lastpos = n;
        lastpos -= 1;
        int lt = (int)((lastpos - bbase) / VPT);
        int le = (int)((lastpos - bbase) % VPT);
        if (tid == lt) s_last = ids[le];
    }

    // Zero LDS accumulators (vectorized).
    {
        float4 z = make_float4(0.f, 0.f, 0.f, 0.f);
        float4* ls4 = (float4*)lsum;
        float4* lc4 = (float4*)lcnt;
        #pragma unroll
        for (int k = tid; k < CHUNK / 4; k += BLOCK) {
            ls4[k] = z;
            lc4[k] = z;
        }
    }
    __syncthreads();

    const int first = s_first;

    // Per-thread run-merge; flush runs to LDS (DS atomics). Guard: ids beyond
    // first+CHUNK-1 (possible only if the block's id range has a gap wider
    // than its element count — needs empty segments) go straight to global
    // atomics; finalize handles anything with gcnts > 0.
    if (nv > 0) {
        int   cur = ids[0];
        float s   = vals[0];
        float c   = 1.0f;
        #pragma unroll
        for (int k = 1; k < VPT; ++k) {
            if (k < nv) {
                if (ids[k] == cur) {
                    s += vals[k];
                    c += 1.0f;
                } else {
                    int off = cur - first;
                    if (off < CHUNK) {
                        atomicAdd(&lsum[off], s);
                        atomicAdd(&lcnt[off], c);
                    } else {
                        atomicAdd(&gsums[cur], s);
                        atomicAdd(&gcnts[cur], c);
                    }
                    cur = ids[k];
                    s = vals[k];
                    c = 1.0f;
                }
            }
        }
        int off = cur - first;
        if (off < CHUNK) {
            atomicAdd(&lsum[off], s);
            atomicAdd(&lcnt[off], c);
        } else {
            atomicAdd(&gsums[cur], s);
            atomicAdd(&gcnts[cur], c);
        }
    }
    __syncthreads();

    // Output: interior segments -> direct mean store (complete by sortedness);
    // edge segments (may straddle blocks) -> global atomics. Span capped at
    // CHUNK; the capped boundary is conservatively treated as an edge.
    int span = s_last - first + 1;
    int lim = (span < CHUNK) ? span : CHUNK;
    for (int idx = tid; idx < lim; idx += BLOCK) {
        float sv = lsum[idx];
        float cv = lcnt[idx];
        int gc = first + idx;
        if (idx == 0 || idx == lim - 1) {
            if (cv > 0.0f) {
                atomicAdd(&gsums[gc], sv);
                atomicAdd(&gcnts[gc], cv);
            }
        } else {
            out[gc] = (cv > 0.0f) ? (sv / cv) : 0.0f;
        }
    }
}

__global__ void finalize_kernel(float* __restrict__ out,
                                const float* __restrict__ gsums,
                                const float* __restrict__ gcnts,
                                int nc) {
    int c = blockIdx.x * blockDim.x + threadIdx.x;
    if (c < nc) {
        float cv = gcnts[c];
        if (cv > 0.0f) {
            out[c] = gsums[c] / cv;   // straddler/fallback segments only
        }
    }
}

extern "C" void kernel_launch(void* const* d_in, const int* in_sizes, int n_in,
                              void* d_out, int out_size, void* d_ws, size_t ws_size,
                              hipStream_t stream) {
    const float* x = (const float*)d_in[0];
    const void* seg = d_in[1];
    const int n = in_sizes[0];     // 16777216
    const int nc = out_size;       // 262144

    float* gsums = (float*)d_ws;          // [nc]
    float* gcnts = (float*)d_ws + nc;     // [nc]
    float* out   = (float*)d_out;

    // Re-zero every call: harness does not re-poison between graph replays.
    // out must start at 0 so untouched (empty) segments read 0.
    hipMemsetAsync(out, 0, (size_t)nc * sizeof(float), stream);
    hipMemsetAsync(gsums, 0, (size_t)2 * nc * sizeof(float), stream);

    const int grid = (int)(((long long)n + CHUNK - 1) / CHUNK);   // 4096
    seg_mean_kernel<<<grid, BLOCK, 0, stream>>>(x, seg, out, gsums, gcnts, n);

    const int fgrid = (nc + BLOCK - 1) / BLOCK;
    finalize_kernel<<<fgrid, BLOCK, 0, stream>>>(out, gsums, gcnts, nc);
}